// Round 14
// baseline (1873.265 us; speedup 1.0000x reference)
//
#include <hip/hip_runtime.h>

#define B 8
#define N 8192
#define S 1024
#define NS 32
#define THREADS 512
#define NPROD_BLK 4
#define NCONS_BLK 252
#define NCONS_WAVE (NCONS_BLK * 8)
constexpr float BN_EPS = 1e-5f;

typedef float v2f __attribute__((ext_vector_type(2)));

struct KParams {
  const float* xyz;
  const float *w1, *b1, *g1, *be1, *m1, *v1;
  const float *w2, *b2, *g2, *be2, *m2, *v2;
  const float *w3, *b3, *g3, *be3, *m3, *v3;
  float* new_xyz;   // d_out (B,S,3)
  float* out_feat;  // d_out + B*S*3 (B,128,S)
  float* ctrs;      // d_ws+2048: (B, S*3) published centers
  unsigned* prog;   // d_ws: per-batch progress counter, 64-int stride
};

// DPP-based full-wave (64-lane) f32 max; result valid in lane 63.
__device__ __forceinline__ float wave_max_to_lane63(float x) {
  int v = __float_as_int(x);
#define DPP_MAX(ctrl)                                                     \
  v = __float_as_int(fmaxf(__int_as_float(v),                             \
      __int_as_float(__builtin_amdgcn_update_dpp(v, v, (ctrl), 0xf, 0xf, \
                                                 false))))
  DPP_MAX(0x111);
  DPP_MAX(0x112);
  DPP_MAX(0x114);
  DPP_MAX(0x118);
  DPP_MAX(0x142);
  DPP_MAX(0x143);
#undef DPP_MAX
  return __int_as_float(v);
}

// Local max over 16 v2f halves + first-occurrence index via prefer-left
// walk-down (exact tie semantics: smallest local index wins).
__device__ __forceinline__ void tree16(const v2f D[8], float& m, int& li) {
  float n1[8], n2[4], n3[2];
#pragma unroll
  for (int i = 0; i < 8; ++i) n1[i] = fmaxf(D[i].x, D[i].y);
#pragma unroll
  for (int i = 0; i < 4; ++i) n2[i] = fmaxf(n1[2 * i], n1[2 * i + 1]);
  n3[0] = fmaxf(n2[0], n2[1]);
  n3[1] = fmaxf(n2[2], n2[3]);
  m = fmaxf(n3[0], n3[1]);
  int c3 = (n3[0] < m) ? 1 : 0;
  float n2s = c3 ? n2[2] : n2[0];
  int c2 = (n2s < m) ? 1 : 0;
  float n1a = c3 ? n1[4] : n1[0];
  float n1b = c3 ? n1[6] : n1[2];
  float n1s = c2 ? n1b : n1a;
  int c1 = (n1s < m) ? 1 : 0;
  float dx0 = c3 ? D[4].x : D[0].x;
  float dx1 = c3 ? D[5].x : D[1].x;
  float dx2 = c3 ? D[6].x : D[2].x;
  float dx3 = c3 ? D[7].x : D[3].x;
  float dxa = c2 ? dx2 : dx0;
  float dxb = c2 ? dx3 : dx1;
  float dxs = c1 ? dxb : dxa;
  int c0 = (dxs < m) ? 1 : 0;
  li = 8 * c3 + 4 * c2 + 2 * c1 + c0;
}

// Wave argmax: max value + owning global index (smallest index on ties,
// since lane order == index order and ballot's first set lane wins).
__device__ __forceinline__ void wave_argmax(float m, int p0, int li,
                                            float& wavemax, int& widx) {
  float wm = wave_max_to_lane63(m);
  wavemax = __int_as_float(__builtin_amdgcn_readlane(__float_as_int(wm), 63));
  unsigned long long bal = __ballot(m == wavemax);
  int firstlane = (int)__builtin_ctzll(bal);
  widx = __builtin_amdgcn_readlane(p0 + li, firstlane);
}

// ---------------------------------------------------------------------------
// Producer: TWO interleaved FPS chains (batches 2*pb, 2*pb+1) per block.
// Rationale (R14): per-round cost was ~1900 cy invariant under every tested
// perturbation -> the fixed term (barrier wake + LDS exchange + reduce-chain
// latency, ~600+ cy) is latency-structural. Two independent chains share one
// barrier and overlap each other's dependent-chain latency with issue work.
// Winner coords come from global (L2 ~220 cy, the 2x128KB LDS mirrors don't
// fit) -- both chains' loads issue back-to-back so the waits overlap.
// s_ctrA written by wave0 lane0 (publishes A); s_ctrB by wave1 lane0
// (publishes B) -- same-wave LDS write->read ordering, no cross-wave race.
// Exact contract-off fp32 distance math -> argmax matches NumPy bit-for-bit;
// ties -> smallest index (prefer-left walk-down + (8191-idx) key low word).
// ---------------------------------------------------------------------------
__device__ __forceinline__ void producer(const KParams& P, char* smem, int pb,
                                         int t, int lane, int w) {
#pragma clang fp contract(off)
  float* s_ctrA = (float*)smem;                       // 12 KB
  float* s_ctrB = (float*)(smem + 12288);             // 12 KB
  unsigned long long(*s_redA)[8] =
      (unsigned long long(*)[8])(smem + 24576);       // 128 B
  unsigned long long(*s_redB)[8] =
      (unsigned long long(*)[8])(smem + 24576 + 128); // 128 B
  const int bA = 2 * pb, bB = 2 * pb + 1;
  const float* baseA = P.xyz + (size_t)bA * N * 3;
  const float* baseB = P.xyz + (size_t)bB * N * 3;
  v2f XA[8], YA[8], ZA[8], DA[8];
  v2f XB[8], YB[8], ZB[8], DB[8];
  const int p0 = t * 16;
  {
    // 16 pts * 3 floats = 12 float4 loads per batch, 16B-aligned.
    const float4* srcA = (const float4*)(baseA + (size_t)p0 * 3);
    const float4* srcB = (const float4*)(baseB + (size_t)p0 * 3);
    float bufA[48], bufB[48];
#pragma unroll
    for (int i = 0; i < 12; ++i) {
      float4 va = srcA[i];
      bufA[4 * i + 0] = va.x; bufA[4 * i + 1] = va.y;
      bufA[4 * i + 2] = va.z; bufA[4 * i + 3] = va.w;
      float4 vb = srcB[i];
      bufB[4 * i + 0] = vb.x; bufB[4 * i + 1] = vb.y;
      bufB[4 * i + 2] = vb.z; bufB[4 * i + 3] = vb.w;
    }
#pragma unroll
    for (int i = 0; i < 8; ++i) {
      XA[i] = (v2f){bufA[6 * i + 0], bufA[6 * i + 3]};
      YA[i] = (v2f){bufA[6 * i + 1], bufA[6 * i + 4]};
      ZA[i] = (v2f){bufA[6 * i + 2], bufA[6 * i + 5]};
      DA[i] = (v2f){3.4e38f, 3.4e38f};  // ref init +inf; min(inf,d)=d, d<=3
      XB[i] = (v2f){bufB[6 * i + 0], bufB[6 * i + 3]};
      YB[i] = (v2f){bufB[6 * i + 1], bufB[6 * i + 4]};
      ZB[i] = (v2f){bufB[6 * i + 2], bufB[6 * i + 5]};
      DB[i] = (v2f){3.4e38f, 3.4e38f};
    }
  }
  float lxA = baseA[0], lyA = baseA[1], lzA = baseA[2];  // start index 0
  float lxB = baseB[0], lyB = baseB[1], lzB = baseB[2];
  if (w == 0 && lane == 0) { s_ctrA[0] = lxA; s_ctrA[1] = lyA; s_ctrA[2] = lzA; }
  if (w == 1 && lane == 0) { s_ctrB[0] = lxB; s_ctrB[1] = lyB; s_ctrB[2] = lzB; }
  for (int r = 1; r < S; ++r) {
    // ---- distance updates, both chains (independent -> overlap) ----
    v2f lxA2 = lxA, lyA2 = lyA, lzA2 = lzA;
    v2f lxB2 = lxB, lyB2 = lyB, lzB2 = lzB;
    // exact: d = ((dx*dx)+(dy*dy))+(dz*dz), contraction off; pk ops round
    // identically to scalar per lane-half.
#pragma unroll
    for (int i = 0; i < 8; ++i) {
      v2f dxa = XA[i] - lxA2, dya = YA[i] - lyA2, dza = ZA[i] - lzA2;
      v2f da = (dxa * dxa + dya * dya) + dza * dza;
      DA[i] = __builtin_elementwise_min(DA[i], da);
      v2f dxb = XB[i] - lxB2, dyb = YB[i] - lyB2, dzb = ZB[i] - lzB2;
      v2f db = (dxb * dxb + dyb * dyb) + dzb * dzb;
      DB[i] = __builtin_elementwise_min(DB[i], db);
    }
    float mA, mB;
    int liA, liB;
    tree16(DA, mA, liA);
    tree16(DB, mB, liB);
    float wavemaxA, wavemaxB;
    int widxA, widxB;
    wave_argmax(mA, p0, liA, wavemaxA, widxA);
    wave_argmax(mB, p0, liB, wavemaxB, widxB);
    unsigned long long keyA =
        ((unsigned long long)__float_as_uint(wavemaxA) << 32) |
        (unsigned)(8191 - widxA);
    unsigned long long keyB =
        ((unsigned long long)__float_as_uint(wavemaxB) << 32) |
        (unsigned)(8191 - widxB);
    if (lane == 0) {
      s_redA[r & 1][w] = keyA;
      s_redB[r & 1][w] = keyB;
    }
    __syncthreads();  // ONE barrier serves both chains
    int biA, biB;
    {  // parallel cross-wave reduce, both chains
      const unsigned long long* sa = s_redA[r & 1];
      const unsigned long long* sb = s_redB[r & 1];
      unsigned long long a0 = sa[0], a1 = sa[1], a2 = sa[2], a3 = sa[3];
      unsigned long long a4 = sa[4], a5 = sa[5], a6 = sa[6], a7 = sa[7];
      unsigned long long b0 = sb[0], b1 = sb[1], b2 = sb[2], b3 = sb[3];
      unsigned long long b4 = sb[4], b5 = sb[5], b6 = sb[6], b7 = sb[7];
      unsigned long long pa = a0 > a1 ? a0 : a1;
      unsigned long long qa = a2 > a3 ? a2 : a3;
      unsigned long long ra = a4 > a5 ? a4 : a5;
      unsigned long long sa2 = a6 > a7 ? a6 : a7;
      unsigned long long ta = pa > qa ? pa : qa;
      unsigned long long ua = ra > sa2 ? ra : sa2;
      unsigned long long ka = ta > ua ? ta : ua;
      biA = 8191 - (int)(unsigned)(ka & 0xffffffffull);
      unsigned long long pb2 = b0 > b1 ? b0 : b1;
      unsigned long long qb = b2 > b3 ? b2 : b3;
      unsigned long long rb = b4 > b5 ? b4 : b5;
      unsigned long long sb2 = b6 > b7 ? b6 : b7;
      unsigned long long tb = pb2 > qb ? pb2 : qb;
      unsigned long long ub = rb > sb2 ? rb : sb2;
      unsigned long long kb = tb > ub ? tb : ub;
      biB = 8191 - (int)(unsigned)(kb & 0xffffffffull);
    }
    // winner coords from global (L2-hit broadcast); both chains' loads issue
    // back-to-back so their latencies overlap.
    const float* cpA = baseA + (size_t)biA * 3;
    const float* cpB = baseB + (size_t)biB * 3;
    float nlxA = cpA[0], nlyA = cpA[1], nlzA = cpA[2];
    float nlxB = cpB[0], nlyB = cpB[1], nlzB = cpB[2];
    lxA = nlxA; lyA = nlyA; lzA = nlzA;
    lxB = nlxB; lyB = nlyB; lzB = nlzB;
    if (w == 0 && lane == 0) {
      s_ctrA[r * 3 + 0] = lxA; s_ctrA[r * 3 + 1] = lyA; s_ctrA[r * 3 + 2] = lzA;
    }
    if (w == 1 && lane == 0) {
      s_ctrB[r * 3 + 0] = lxB; s_ctrB[r * 3 + 1] = lyB; s_ctrB[r * 3 + 2] = lzB;
    }
    // Lagged publish: wave 0 -> batch A, wave 1 -> batch B. Release prog for
    // chunk k-1 (stores drained 8 rounds ago), then relaxed-store chunk k.
    if ((r & 7) == 7 && w < 2) {
      const int bb = (w == 0) ? bA : bB;
      const float* sc = (w == 0) ? s_ctrA : s_ctrB;
      int k8 = r >> 3;
      if (lane == 0 && k8 >= 1)
        __hip_atomic_store(&P.prog[bb * 64], (unsigned)(k8 * 8),
                           __ATOMIC_RELEASE, __HIP_MEMORY_SCOPE_AGENT);
      int cbase = (r - 7) * 3;
      if (lane < 24)
        __hip_atomic_store(P.ctrs + (size_t)bb * (S * 3) + cbase + lane,
                           sc[cbase + lane], __ATOMIC_RELAXED,
                           __HIP_MEMORY_SCOPE_AGENT);
    }
  }
  __syncthreads();  // s_ctr complete before cooperative writeout
  if (w == 0 && lane == 0)
    __hip_atomic_store(&P.prog[bA * 64], (unsigned)S, __ATOMIC_RELEASE,
                       __HIP_MEMORY_SCOPE_AGENT);
  if (w == 1 && lane == 0)
    __hip_atomic_store(&P.prog[bB * 64], (unsigned)S, __ATOMIC_RELEASE,
                       __HIP_MEMORY_SCOPE_AGENT);
  float* oA = P.new_xyz + (size_t)bA * S * 3;
  float* oB = P.new_xyz + (size_t)bB * S * 3;
  for (int i = t; i < (S * 3) / 4; i += THREADS) {
    ((float4*)oA)[i] = ((const float4*)s_ctrA)[i];
    ((float4*)oB)[i] = ((const float4*)s_ctrB)[i];
  }
}

// ---------------------------------------------------------------------------
// Consumer: one wave per center (8 waves/block). Spin (s_sleep backoff) until
// the producer publishes center (b,s); ball query fused with coord gather;
// 3-layer BN-folded MLP + max. No block barriers (same-wave LDS RAW only).
// ---------------------------------------------------------------------------
__device__ __forceinline__ void consumer(const KParams& P, char* smem, int cid,
                                         int t, int lane, int w) {
#pragma clang fp contract(off)
  constexpr float R2 = (float)(0.2 * 0.2);
  float* h = (float*)smem + w * (NS * 64);              // 8 KB per wave
  float* cs = (float*)smem + 8 * NS * 64 + w * (NS * 4);
  const unsigned gw = cid * 8 + w;  // global consumer wave id, 0..2015
  // BN-folded weights, loaded once per wave (registers)
  float sv1 = P.g1[lane] / sqrtf(P.v1[lane] + BN_EPS);
  float bb1 = (P.b1[lane] - P.m1[lane]) * sv1 + P.be1[lane];
  float w1x = P.w1[lane * 3 + 0] * sv1, w1y = P.w1[lane * 3 + 1] * sv1,
        w1z = P.w1[lane * 3 + 2] * sv1;
  float sv2 = P.g2[lane] / sqrtf(P.v2[lane] + BN_EPS);
  float bb2 = (P.b2[lane] - P.m2[lane]) * sv2 + P.be2[lane];
  float W2[64];
#pragma unroll
  for (int k = 0; k < 64; k += 4) {
    float4 q = *(const float4*)(P.w2 + lane * 64 + k);
    W2[k + 0] = q.x * sv2; W2[k + 1] = q.y * sv2;
    W2[k + 2] = q.z * sv2; W2[k + 3] = q.w * sv2;
  }
  float sva = P.g3[lane] / sqrtf(P.v3[lane] + BN_EPS);
  float bba = (P.b3[lane] - P.m3[lane]) * sva + P.be3[lane];
  float svb = P.g3[lane + 64] / sqrtf(P.v3[lane + 64] + BN_EPS);
  float bbb = (P.b3[lane + 64] - P.m3[lane + 64]) * svb + P.be3[lane + 64];
  float Wa[64], Wb[64];
#pragma unroll
  for (int k = 0; k < 64; k += 4) {
    float4 qa = *(const float4*)(P.w3 + lane * 64 + k);
    Wa[k + 0] = qa.x * sva; Wa[k + 1] = qa.y * sva;
    Wa[k + 2] = qa.z * sva; Wa[k + 3] = qa.w * sva;
    float4 qb = *(const float4*)(P.w3 + (lane + 64) * 64 + k);
    Wb[k + 0] = qb.x * svb; Wb[k + 1] = qb.y * svb;
    Wb[k + 2] = qb.z * svb; Wb[k + 3] = qb.w * svb;
  }
  for (unsigned c = gw; c < B * S; c += NCONS_WAVE) {
    const int b = c & 7;
    const int s = c >> 3;
    while (__hip_atomic_load(&P.prog[b * 64], __ATOMIC_RELAXED,
                             __HIP_MEMORY_SCOPE_AGENT) <= (unsigned)s)
      __builtin_amdgcn_s_sleep(8);
    (void)__hip_atomic_load(&P.prog[b * 64], __ATOMIC_ACQUIRE,
                            __HIP_MEMORY_SCOPE_AGENT);
    const float* cg = P.ctrs + (size_t)b * (S * 3) + s * 3;
    float cx = __hip_atomic_load(cg + 0, __ATOMIC_RELAXED,
                                 __HIP_MEMORY_SCOPE_AGENT);
    float cy = __hip_atomic_load(cg + 1, __ATOMIC_RELAXED,
                                 __HIP_MEMORY_SCOPE_AGENT);
    float cz = __hip_atomic_load(cg + 2, __ATOMIC_RELAXED,
                                 __HIP_MEMORY_SCOPE_AGENT);
    const float* base = P.xyz + (size_t)b * N * 3;
    // ball query fused with coord gather: finder lane scatters coords to cs
    int cnt = 0;
    for (int c0 = 0; c0 < N && cnt < NS; c0 += 64) {
      int p = c0 + lane;
      float x = base[p * 3], y = base[p * 3 + 1], z = base[p * 3 + 2];
      float dx = x - cx, dy = y - cy, dz = z - cz;
      float d = (dx * dx + dy * dy) + dz * dz;
      bool v = d < R2;  // strict <, exact fp32: matches reference
      unsigned long long mk = __ballot(v);
      int rank = cnt + __popcll(mk & ((1ull << lane) - 1ull));
      if (v && rank < NS) {
        cs[rank * 4 + 0] = x; cs[rank * 4 + 1] = y; cs[rank * 4 + 2] = z;
      }
      cnt += (int)__popcll(mk);
    }
    if (cnt < NS) {  // pad -> point 0 coords (pytorch3d clamp semantics)
      float x0 = base[0], y0 = base[1], z0 = base[2];
      for (int j = cnt + lane; j < NS; j += 64) {
        cs[j * 4 + 0] = x0; cs[j * 4 + 1] = y0; cs[j * 4 + 2] = z0;
      }
    }
    // layer 1: 3 -> 64
    for (int n = 0; n < NS; ++n) {
      float a = fmaf(w1x, cs[n * 4 + 0],
                     fmaf(w1y, cs[n * 4 + 1], fmaf(w1z, cs[n * 4 + 2], bb1)));
      h[n * 64 + lane] = fmaxf(a, 0.f);
    }
    // layer 2: 64 -> 64 (in-place row overwrite, wave-lockstep safe)
    for (int n = 0; n < NS; ++n) {
      float acc = bb2;
#pragma unroll
      for (int k = 0; k < 64; k += 4) {
        float4 q = *(const float4*)(h + n * 64 + k);
        acc = fmaf(W2[k + 0], q.x, acc);
        acc = fmaf(W2[k + 1], q.y, acc);
        acc = fmaf(W2[k + 2], q.z, acc);
        acc = fmaf(W2[k + 3], q.w, acc);
      }
      h[n * 64 + lane] = fmaxf(acc, 0.f);
    }
    // layer 3: 64 -> 128, both halves per pass, fused max over samples
    float mxa = 0.f, mxb = 0.f;
    for (int n = 0; n < NS; ++n) {
      float acca = bba, accb = bbb;
#pragma unroll
      for (int k = 0; k < 64; k += 4) {
        float4 q = *(const float4*)(h + n * 64 + k);
        acca = fmaf(Wa[k + 0], q.x, acca);
        acca = fmaf(Wa[k + 1], q.y, acca);
        acca = fmaf(Wa[k + 2], q.z, acca);
        acca = fmaf(Wa[k + 3], q.w, acca);
        accb = fmaf(Wb[k + 0], q.x, accb);
        accb = fmaf(Wb[k + 1], q.y, accb);
        accb = fmaf(Wb[k + 2], q.z, accb);
        accb = fmaf(Wb[k + 3], q.w, accb);
      }
      mxa = fmaxf(mxa, acca);
      mxb = fmaxf(mxb, accb);
    }
    P.out_feat[((size_t)b * 128 + lane) * S + s] = mxa;
    P.out_feat[((size_t)b * 128 + 64 + lane) * S + s] = mxb;
  }
}

// ---------------------------------------------------------------------------
__global__ void __attribute__((amdgpu_flat_work_group_size(THREADS, THREADS),
                               amdgpu_waves_per_eu(2, 2)))
k_fused(KParams P) {
  extern __shared__ char smem[];
  const int t = threadIdx.x;
  const int lane = t & 63;
  const int w = t >> 6;
  if (blockIdx.x < NPROD_BLK)
    producer(P, smem, blockIdx.x, t, lane, w);
  else
    consumer(P, smem, blockIdx.x - NPROD_BLK, t, lane, w);
}

// ---------------------------------------------------------------------------
extern "C" void kernel_launch(void* const* d_in, const int* in_sizes, int n_in,
                              void* d_out, int out_size, void* d_ws,
                              size_t ws_size, hipStream_t stream) {
  KParams P;
  P.xyz = (const float*)d_in[0];
  P.w1 = (const float*)d_in[1];  P.b1 = (const float*)d_in[2];
  P.g1 = (const float*)d_in[3];  P.be1 = (const float*)d_in[4];
  P.m1 = (const float*)d_in[5];  P.v1 = (const float*)d_in[6];
  P.w2 = (const float*)d_in[7];  P.b2 = (const float*)d_in[8];
  P.g2 = (const float*)d_in[9];  P.be2 = (const float*)d_in[10];
  P.m2 = (const float*)d_in[11]; P.v2 = (const float*)d_in[12];
  P.w3 = (const float*)d_in[13]; P.b3 = (const float*)d_in[14];
  P.g3 = (const float*)d_in[15]; P.be3 = (const float*)d_in[16];
  P.m3 = (const float*)d_in[17]; P.v3 = (const float*)d_in[18];
  float* out = (float*)d_out;
  P.new_xyz = out;
  P.out_feat = out + (size_t)B * S * 3;
  P.prog = (unsigned*)d_ws;                       // 8 x 64 u32 = 2 KB
  P.ctrs = (float*)((char*)d_ws + 2048);          // 96 KB

  // d_ws is re-poisoned to 0xAA before every timed launch: zero the progress
  // counters (async, graph-capturable) or consumers would see garbage.
  hipMemsetAsync(d_ws, 0, 2048, stream);

  // Plain launch (coop costs ~55 us, measured). Shmem padded to 84 KB so
  // 2 blocks/CU cannot co-reside (2x84 > 160 KB) -> no consumer block can
  // share a CU with a producer block.
  dim3 grid(NPROD_BLK + NCONS_BLK), blk(THREADS);
  size_t shmem = 86016;  // consumer needs 68 KB; padded to 84 KB (see above)
  k_fused<<<grid, blk, shmem, stream>>>(P);
}

// Round 15
// 907.622 us; speedup vs baseline: 2.0639x; 2.0639x over previous
//
#include <hip/hip_runtime.h>

#define B 8
#define N 8192
#define S 1024
#define NS 32
#define THREADS 256
#define NCONS_BLK 248
#define NCONS_WAVE (NCONS_BLK * 4)
constexpr float BN_EPS = 1e-5f;

typedef float v2f __attribute__((ext_vector_type(2)));

struct KParams {
  const float* xyz;
  const float *w1, *b1, *g1, *be1, *m1, *v1;
  const float *w2, *b2, *g2, *be2, *m2, *v2;
  const float *w3, *b3, *g3, *be3, *m3, *v3;
  float* new_xyz;   // d_out (B,S,3)
  float* out_feat;  // d_out + B*S*3 (B,128,S)
  float* ctrs;      // d_ws+2048: (B, S*3) published centers
  unsigned* prog;   // d_ws: per-batch progress counter, 64-int stride
};

// DPP-based full-wave (64-lane) f32 max; result valid in lane 63.
__device__ __forceinline__ float wave_max_to_lane63(float x) {
  int v = __float_as_int(x);
#define DPP_MAX(ctrl)                                                     \
  v = __float_as_int(fmaxf(__int_as_float(v),                             \
      __int_as_float(__builtin_amdgcn_update_dpp(v, v, (ctrl), 0xf, 0xf, \
                                                 false))))
  DPP_MAX(0x111);
  DPP_MAX(0x112);
  DPP_MAX(0x114);
  DPP_MAX(0x118);
  DPP_MAX(0x142);
  DPP_MAX(0x143);
#undef DPP_MAX
  return __int_as_float(v);
}

// ---------------------------------------------------------------------------
// R15 = R13 restored (session best, 913 us total): R14's two-chain
// interleave spilled its 128-VGPR doubled payload (VGPR_Count=120) and
// regressed 2.1x. Structural note for posterity: FPS's 1023 sequential
// argmax rounds cost ~1900 cy each, measured invariant across wave count,
// spill state, barrier mechanism, publish placement, and register budget
// -> latency-structural serial chain (~810 us), with ball+gather+MLP
// (~240 us of work) fully hidden inside it by the producer-consumer
// megakernel. HBM 0.4%, VALU 13% chip-wide: not a HW roofline; an Amdahl
// chain on 8/256 CUs under bit-exact selection semantics.
//
// Producer: FPS, 4 waves (1/SIMD), 32 pts/thread. One s_barrier per round
// (R11: spin-exchange is ~100 us worse), parallel 4-key LDS reduce, float4
// LDS mirror for 1-instr winner-coord broadcast, lagged publish every 8
// rounds. Exact contract-off fp32 distance math -> argmax matches NumPy
// bit-for-bit; ties -> smallest index (prefer-left walk-down + (8191-idx)
// key low word).
// ---------------------------------------------------------------------------
__device__ __forceinline__ void producer(const KParams& P, char* smem, int b,
                                         int t, int lane, int w) {
#pragma clang fp contract(off)
  float4* s_xyz4 = (float4*)smem;                       // 128 KB
  float* s_ctr = (float*)(smem + 131072);               // 12 KB
  unsigned long long(*s_red)[4] =
      (unsigned long long(*)[4])(smem + 131072 + 12288);
  const float* base = P.xyz + (size_t)b * N * 3;
  v2f X[16], Y[16], Z[16], D[16];
  const int p0 = t * 32;
  {
    // 32 pts * 3 floats = 24 float4 loads, 16B-aligned (t*384 bytes);
    // mirrored float4-strided into LDS for 1-instr winner-coord broadcast.
    const float4* src = (const float4*)(base + (size_t)p0 * 3);
    float buf[96];
#pragma unroll
    for (int i = 0; i < 24; ++i) {
      float4 v = src[i];
      buf[4 * i + 0] = v.x; buf[4 * i + 1] = v.y;
      buf[4 * i + 2] = v.z; buf[4 * i + 3] = v.w;
    }
#pragma unroll
    for (int k = 0; k < 32; ++k)
      s_xyz4[p0 + k] =
          make_float4(buf[3 * k], buf[3 * k + 1], buf[3 * k + 2], 0.f);
#pragma unroll
    for (int i = 0; i < 16; ++i) {
      X[i] = (v2f){buf[6 * i + 0], buf[6 * i + 3]};
      Y[i] = (v2f){buf[6 * i + 1], buf[6 * i + 4]};
      Z[i] = (v2f){buf[6 * i + 2], buf[6 * i + 5]};
      D[i] = (v2f){3.4e38f, 3.4e38f};  // ref init +inf; min(inf,d)=d, d<=3
    }
  }
  float lx = base[0], ly = base[1], lz = base[2];  // start index 0
  if (t == 0) { s_ctr[0] = lx; s_ctr[1] = ly; s_ctr[2] = lz; }
  for (int r = 1; r < S; ++r) {
    v2f lx2 = lx, ly2 = ly, lz2 = lz;
    // exact: d = ((dx*dx)+(dy*dy))+(dz*dz), contraction off; pk ops round
    // identically to scalar per lane-half.
#pragma unroll
    for (int i = 0; i < 16; ++i) {
      v2f dx = X[i] - lx2, dy = Y[i] - ly2, dz = Z[i] - lz2;
      v2f d = (dx * dx + dy * dy) + dz * dz;
      D[i] = __builtin_elementwise_min(D[i], d);
    }
    // local max tree over 32 halves; prefer-left walk-down == first index
    float n1[16], n2[8], n3[4], n4[2];
#pragma unroll
    for (int i = 0; i < 16; ++i) n1[i] = fmaxf(D[i].x, D[i].y);
#pragma unroll
    for (int i = 0; i < 8; ++i) n2[i] = fmaxf(n1[2 * i], n1[2 * i + 1]);
#pragma unroll
    for (int i = 0; i < 4; ++i) n3[i] = fmaxf(n2[2 * i], n2[2 * i + 1]);
    n4[0] = fmaxf(n3[0], n3[1]);
    n4[1] = fmaxf(n3[2], n3[3]);
    float m = fmaxf(n4[0], n4[1]);
    int c4 = (n4[0] < m) ? 1 : 0;
    float n3s = c4 ? n3[2] : n3[0];
    int c3 = (n3s < m) ? 1 : 0;
    float n2a = c4 ? n2[4] : n2[0];
    float n2b = c4 ? n2[6] : n2[2];
    float n2s = c3 ? n2b : n2a;
    int c2 = (n2s < m) ? 1 : 0;
    float n1a = c4 ? n1[8] : n1[0];
    float n1b = c4 ? n1[10] : n1[2];
    float n1c = c4 ? n1[12] : n1[4];
    float n1d = c4 ? n1[14] : n1[6];
    float n1e = c3 ? n1c : n1a;
    float n1f = c3 ? n1d : n1b;
    float n1s = c2 ? n1f : n1e;
    int c1 = (n1s < m) ? 1 : 0;
    float e0 = c4 ? D[8].x : D[0].x;
    float e1 = c4 ? D[9].x : D[1].x;
    float e2 = c4 ? D[10].x : D[2].x;
    float e3 = c4 ? D[11].x : D[3].x;
    float e4 = c4 ? D[12].x : D[4].x;
    float e5 = c4 ? D[13].x : D[5].x;
    float e6 = c4 ? D[14].x : D[6].x;
    float e7 = c4 ? D[15].x : D[7].x;
    float f0 = c3 ? e4 : e0;
    float f1 = c3 ? e5 : e1;
    float f2 = c3 ? e6 : e2;
    float f3 = c3 ? e7 : e3;
    float g0 = c2 ? f2 : f0;
    float g1 = c2 ? f3 : f1;
    float dxs = c1 ? g1 : g0;
    int c0 = (dxs < m) ? 1 : 0;
    int li = 16 * c4 + 8 * c3 + 4 * c2 + 2 * c1 + c0;
    // wave max via DPP; index recovery via ballot (lane order == index order)
    float wm = wave_max_to_lane63(m);
    float wavemax =
        __int_as_float(__builtin_amdgcn_readlane(__float_as_int(wm), 63));
    unsigned long long bal = __ballot(m == wavemax);
    int firstlane = (int)__builtin_ctzll(bal);
    int widx = __builtin_amdgcn_readlane(p0 + li, firstlane);
    unsigned long long key =
        ((unsigned long long)__float_as_uint(wavemax) << 32) |
        (unsigned)(8191 - widx);
    if (lane == 0) s_red[r & 1][w] = key;
    __syncthreads();
    {  // parallel cross-wave reduce: 4 broadcast LDS reads + u64 max tree
      const unsigned long long* sr = s_red[r & 1];
      unsigned long long k0 = sr[0], k1 = sr[1], k2 = sr[2], k3 = sr[3];
      unsigned long long a = k0 > k1 ? k0 : k1;
      unsigned long long c = k2 > k3 ? k2 : k3;
      unsigned long long kmax = a > c ? a : c;
      const int bi = 8191 - (int)(unsigned)(kmax & 0xffffffffull);
      float4 cc = s_xyz4[bi];  // ONE ds_read_b128, broadcast
      lx = cc.x; ly = cc.y; lz = cc.z;
    }
    if (t == 0) {
      s_ctr[r * 3 + 0] = lx; s_ctr[r * 3 + 1] = ly; s_ctr[r * 3 + 2] = lz;
    }
    // Lagged publish: release prog for chunk k-1 (its stores drained 8
    // rounds ago -> vmcnt(0) instant), then relaxed-store chunk k's coords.
    if (w == 0 && (r & 7) == 7) {
      int k8 = r >> 3;
      if (lane == 0 && k8 >= 1)
        __hip_atomic_store(&P.prog[b * 64], (unsigned)(k8 * 8),
                           __ATOMIC_RELEASE, __HIP_MEMORY_SCOPE_AGENT);
      int cbase = (r - 7) * 3;
      if (lane < 24)
        __hip_atomic_store(P.ctrs + (size_t)b * (S * 3) + cbase + lane,
                           s_ctr[cbase + lane], __ATOMIC_RELAXED,
                           __HIP_MEMORY_SCOPE_AGENT);
    }
  }
  __syncthreads();
  if (w == 0 && lane == 0)  // final release covers the last 2 chunks
    __hip_atomic_store(&P.prog[b * 64], (unsigned)S, __ATOMIC_RELEASE,
                       __HIP_MEMORY_SCOPE_AGENT);
  float* o = P.new_xyz + (size_t)b * S * 3;
  for (int i = t; i < (S * 3) / 4; i += THREADS)
    ((float4*)o)[i] = ((const float4*)s_ctr)[i];
}

// ---------------------------------------------------------------------------
// Consumer: one wave per center (4 waves/block). Spin (s_sleep backoff) until
// the producer publishes center (b,s); ball query fused with coord gather;
// 3-layer BN-folded MLP + max. No block barriers (same-wave LDS RAW only).
// ---------------------------------------------------------------------------
__device__ __forceinline__ void consumer(const KParams& P, char* smem, int cid,
                                         int t, int lane, int w) {
#pragma clang fp contract(off)
  constexpr float R2 = (float)(0.2 * 0.2);
  float* h = (float*)smem + w * (NS * 64);              // 8 KB per wave
  float* cs = (float*)smem + 4 * NS * 64 + w * (NS * 4);
  const unsigned gw = cid * 4 + w;  // global consumer wave id, 0..991
  // BN-folded weights, loaded once per wave (registers)
  float sv1 = P.g1[lane] / sqrtf(P.v1[lane] + BN_EPS);
  float bb1 = (P.b1[lane] - P.m1[lane]) * sv1 + P.be1[lane];
  float w1x = P.w1[lane * 3 + 0] * sv1, w1y = P.w1[lane * 3 + 1] * sv1,
        w1z = P.w1[lane * 3 + 2] * sv1;
  float sv2 = P.g2[lane] / sqrtf(P.v2[lane] + BN_EPS);
  float bb2 = (P.b2[lane] - P.m2[lane]) * sv2 + P.be2[lane];
  float W2[64];
#pragma unroll
  for (int k = 0; k < 64; k += 4) {
    float4 q = *(const float4*)(P.w2 + lane * 64 + k);
    W2[k + 0] = q.x * sv2; W2[k + 1] = q.y * sv2;
    W2[k + 2] = q.z * sv2; W2[k + 3] = q.w * sv2;
  }
  float sva = P.g3[lane] / sqrtf(P.v3[lane] + BN_EPS);
  float bba = (P.b3[lane] - P.m3[lane]) * sva + P.be3[lane];
  float svb = P.g3[lane + 64] / sqrtf(P.v3[lane + 64] + BN_EPS);
  float bbb = (P.b3[lane + 64] - P.m3[lane + 64]) * svb + P.be3[lane + 64];
  float Wa[64], Wb[64];
#pragma unroll
  for (int k = 0; k < 64; k += 4) {
    float4 qa = *(const float4*)(P.w3 + lane * 64 + k);
    Wa[k + 0] = qa.x * sva; Wa[k + 1] = qa.y * sva;
    Wa[k + 2] = qa.z * sva; Wa[k + 3] = qa.w * sva;
    float4 qb = *(const float4*)(P.w3 + (lane + 64) * 64 + k);
    Wb[k + 0] = qb.x * svb; Wb[k + 1] = qb.y * svb;
    Wb[k + 2] = qb.z * svb; Wb[k + 3] = qb.w * svb;
  }
  for (unsigned c = gw; c < B * S; c += NCONS_WAVE) {
    const int b = c & 7;
    const int s = c >> 3;
    while (__hip_atomic_load(&P.prog[b * 64], __ATOMIC_RELAXED,
                             __HIP_MEMORY_SCOPE_AGENT) <= (unsigned)s)
      __builtin_amdgcn_s_sleep(8);
    (void)__hip_atomic_load(&P.prog[b * 64], __ATOMIC_ACQUIRE,
                            __HIP_MEMORY_SCOPE_AGENT);
    const float* cg = P.ctrs + (size_t)b * (S * 3) + s * 3;
    float cx = __hip_atomic_load(cg + 0, __ATOMIC_RELAXED,
                                 __HIP_MEMORY_SCOPE_AGENT);
    float cy = __hip_atomic_load(cg + 1, __ATOMIC_RELAXED,
                                 __HIP_MEMORY_SCOPE_AGENT);
    float cz = __hip_atomic_load(cg + 2, __ATOMIC_RELAXED,
                                 __HIP_MEMORY_SCOPE_AGENT);
    const float* base = P.xyz + (size_t)b * N * 3;
    // ball query fused with coord gather: finder lane scatters coords to cs
    int cnt = 0;
    for (int c0 = 0; c0 < N && cnt < NS; c0 += 64) {
      int p = c0 + lane;
      float x = base[p * 3], y = base[p * 3 + 1], z = base[p * 3 + 2];
      float dx = x - cx, dy = y - cy, dz = z - cz;
      float d = (dx * dx + dy * dy) + dz * dz;
      bool v = d < R2;  // strict <, exact fp32: matches reference
      unsigned long long mk = __ballot(v);
      int rank = cnt + __popcll(mk & ((1ull << lane) - 1ull));
      if (v && rank < NS) {
        cs[rank * 4 + 0] = x; cs[rank * 4 + 1] = y; cs[rank * 4 + 2] = z;
      }
      cnt += (int)__popcll(mk);
    }
    if (cnt < NS) {  // pad -> point 0 coords (pytorch3d clamp semantics)
      float x0 = base[0], y0 = base[1], z0 = base[2];
      for (int j = cnt + lane; j < NS; j += 64) {
        cs[j * 4 + 0] = x0; cs[j * 4 + 1] = y0; cs[j * 4 + 2] = z0;
      }
    }
    // layer 1: 3 -> 64
    for (int n = 0; n < NS; ++n) {
      float a = fmaf(w1x, cs[n * 4 + 0],
                     fmaf(w1y, cs[n * 4 + 1], fmaf(w1z, cs[n * 4 + 2], bb1)));
      h[n * 64 + lane] = fmaxf(a, 0.f);
    }
    // layer 2: 64 -> 64 (in-place row overwrite, wave-lockstep safe)
    for (int n = 0; n < NS; ++n) {
      float acc = bb2;
#pragma unroll
      for (int k = 0; k < 64; k += 4) {
        float4 q = *(const float4*)(h + n * 64 + k);
        acc = fmaf(W2[k + 0], q.x, acc);
        acc = fmaf(W2[k + 1], q.y, acc);
        acc = fmaf(W2[k + 2], q.z, acc);
        acc = fmaf(W2[k + 3], q.w, acc);
      }
      h[n * 64 + lane] = fmaxf(acc, 0.f);
    }
    // layer 3: 64 -> 128, both halves per pass, fused max over samples
    float mxa = 0.f, mxb = 0.f;
    for (int n = 0; n < NS; ++n) {
      float acca = bba, accb = bbb;
#pragma unroll
      for (int k = 0; k < 64; k += 4) {
        float4 q = *(const float4*)(h + n * 64 + k);
        acca = fmaf(Wa[k + 0], q.x, acca);
        acca = fmaf(Wa[k + 1], q.y, acca);
        acca = fmaf(Wa[k + 2], q.z, acca);
        acca = fmaf(Wa[k + 3], q.w, acca);
        accb = fmaf(Wb[k + 0], q.x, accb);
        accb = fmaf(Wb[k + 1], q.y, accb);
        accb = fmaf(Wb[k + 2], q.z, accb);
        accb = fmaf(Wb[k + 3], q.w, accb);
      }
      mxa = fmaxf(mxa, acca);
      mxb = fmaxf(mxb, accb);
    }
    P.out_feat[((size_t)b * 128 + lane) * S + s] = mxa;
    P.out_feat[((size_t)b * 128 + 64 + lane) * S + s] = mxb;
  }
}

// ---------------------------------------------------------------------------
__global__ void __attribute__((amdgpu_flat_work_group_size(THREADS, THREADS),
                               amdgpu_waves_per_eu(1, 1)))
k_fused(KParams P) {
  extern __shared__ char smem[];
  const int t = threadIdx.x;
  const int lane = t & 63;
  const int w = t >> 6;
  if (blockIdx.x < B)
    producer(P, smem, blockIdx.x, t, lane, w);
  else
    consumer(P, smem, blockIdx.x - B, t, lane, w);
}

// ---------------------------------------------------------------------------
extern "C" void kernel_launch(void* const* d_in, const int* in_sizes, int n_in,
                              void* d_out, int out_size, void* d_ws,
                              size_t ws_size, hipStream_t stream) {
  KParams P;
  P.xyz = (const float*)d_in[0];
  P.w1 = (const float*)d_in[1];  P.b1 = (const float*)d_in[2];
  P.g1 = (const float*)d_in[3];  P.be1 = (const float*)d_in[4];
  P.m1 = (const float*)d_in[5];  P.v1 = (const float*)d_in[6];
  P.w2 = (const float*)d_in[7];  P.b2 = (const float*)d_in[8];
  P.g2 = (const float*)d_in[9];  P.be2 = (const float*)d_in[10];
  P.m2 = (const float*)d_in[11]; P.v2 = (const float*)d_in[12];
  P.w3 = (const float*)d_in[13]; P.b3 = (const float*)d_in[14];
  P.g3 = (const float*)d_in[15]; P.be3 = (const float*)d_in[16];
  P.m3 = (const float*)d_in[17]; P.v3 = (const float*)d_in[18];
  float* out = (float*)d_out;
  P.new_xyz = out;
  P.out_feat = out + (size_t)B * S * 3;
  P.prog = (unsigned*)d_ws;                       // 8 x 64 u32 = 2 KB
  P.ctrs = (float*)((char*)d_ws + 2048);          // 96 KB

  // d_ws is re-poisoned to 0xAA before every timed launch: zero the progress
  // counters (async, graph-capturable) or consumers would see garbage.
  hipMemsetAsync(d_ws, 0, 2048, stream);

  // Plain launch (coop costs ~55 us, measured R10-vs-R11 gap). 256 blocks x
  // 140 KB LDS -> 1 block/CU; correctness does not require co-residency
  // (late consumer blocks find prog already advanced and just process).
  dim3 grid(B + NCONS_BLK), blk(THREADS);
  size_t shmem = 131072 + 12288 + 256;  // producer overlay is the max
  k_fused<<<grid, blk, shmem, stream>>>(P);
}